// Round 7
// baseline (642.521 us; speedup 1.0000x reference)
//
#include <hip/hip_runtime.h>
#include <hip/hip_bf16.h>
#include <math.h>

// ---------------------------------------------------------------------------
// RESKnorm GCN, CSR-based (no float atomics), f32 message matrix.
//   CSR build: histogram + 3-phase scan + TWO-PASS BINNED permutation:
//     phase A: scatter edges into their 128-node bucket's CSR region of a tmp
//              buffer (random only within ~16KB; packed 8B payload
//              {src[17b] | tgtlocal[7b], wbits}).
//     phase B: one block per bucket; contiguous read of tmp region, exact
//              per-node placement via LDS cursors (order within a node's edge
//              list is arbitrary -- sum is order-insensitive at f32 tolerance).
//   Per layer: S = X@W+b (lin), then quarter-wave aggregation (16 edges in
//   flight per wave), fused epilogue (relu / relu+GN+residual / log_softmax).
// N=50000, E=800000, NFEAT=128, NHID=64, NCLASS=40, GROUPS=32 (2 ch/group)
// ---------------------------------------------------------------------------

#define EPS 1e-5f
#define SCAN_BLK 256
#define BSHIFT 7
#define BW 128  // nodes per bucket

// ---------------- CSR build ----------------
__global__ void count_kernel(const int* __restrict__ tgt, int* __restrict__ cnt,
                             int E) {
    int e = blockIdx.x * blockDim.x + threadIdx.x;
    if (e < E) atomicAdd(&cnt[tgt[e]], 1);
}

__global__ void scan_p1(const int* __restrict__ cnt, int* __restrict__ bsum,
                        int n) {
    __shared__ int lds[SCAN_BLK];
    int i = blockIdx.x * SCAN_BLK + threadIdx.x;
    lds[threadIdx.x] = (i < n) ? cnt[i] : 0;
    __syncthreads();
    for (int off = SCAN_BLK / 2; off; off >>= 1) {
        if (threadIdx.x < off) lds[threadIdx.x] += lds[threadIdx.x + off];
        __syncthreads();
    }
    if (threadIdx.x == 0) bsum[blockIdx.x] = lds[0];
}

__global__ void scan_p2(int* __restrict__ bsum, int nblocks) {
    __shared__ int lds[1024];
    int tid = threadIdx.x;
    int v = (tid < nblocks) ? bsum[tid] : 0;
    lds[tid] = v;
    __syncthreads();
    for (int off = 1; off < 1024; off <<= 1) {
        int t = (tid >= off) ? lds[tid - off] : 0;
        __syncthreads();
        lds[tid] += t;
        __syncthreads();
    }
    if (tid < nblocks) bsum[tid] = lds[tid] - v;  // exclusive
}

__global__ void scan_p3(const int* __restrict__ cnt, const int* __restrict__ bsum,
                        int* __restrict__ rowptr, int n) {
    __shared__ int lds[SCAN_BLK];
    int i = blockIdx.x * SCAN_BLK + threadIdx.x;
    int v = (i < n) ? cnt[i] : 0;
    lds[threadIdx.x] = v;
    __syncthreads();
    for (int off = 1; off < SCAN_BLK; off <<= 1) {
        int t = (threadIdx.x >= off) ? lds[threadIdx.x - off] : 0;
        __syncthreads();
        lds[threadIdx.x] += t;
        __syncthreads();
    }
    int excl = bsum[blockIdx.x] + lds[threadIdx.x] - v;
    if (i < n) {
        rowptr[i] = excl;
        if (i == n - 1) rowptr[n] = excl + v;
    }
}

// bucket cursors start at the bucket's CSR base
__global__ void bcur_init(const int* __restrict__ rowptr, int* __restrict__ bcur,
                          int nb) {
    int b = blockIdx.x * blockDim.x + threadIdx.x;
    if (b < nb) bcur[b] = rowptr[b << BSHIFT];
}

// phase A: edge -> bucket region of tmp; payload {src | tgtlocal<<17, wbits}
__global__ void binA_kernel(const int* __restrict__ src, const int* __restrict__ tgt,
                            const float* __restrict__ mv, int* __restrict__ bcur,
                            long long* __restrict__ tmp, int E) {
    int e = blockIdx.x * blockDim.x + threadIdx.x;
    if (e >= E) return;
    int t = tgt[e];
    int pos = atomicAdd(&bcur[t >> BSHIFT], 1);
    unsigned lo = (unsigned)src[e] | ((unsigned)(t & (BW - 1)) << 17);
    long long v = (long long)lo | ((long long)__float_as_int(mv[e]) << 32);
    tmp[pos] = v;
}

// phase B: one block per bucket; exact per-node placement via LDS cursors
__global__ void binB_kernel(const int* __restrict__ rowptr,
                            const long long* __restrict__ tmp,
                            long long* __restrict__ ep, int N) {
    __shared__ int c[BW];
    int node0 = blockIdx.x << BSHIFT;
    int nLocal = min(BW, N - node0);
    for (int i = threadIdx.x; i < nLocal; i += blockDim.x)
        c[i] = rowptr[node0 + i];
    __syncthreads();
    int beg = rowptr[node0];
    int end = rowptr[node0 + nLocal];
    for (int j = beg + threadIdx.x; j < end; j += blockDim.x) {
        long long p = tmp[j];
        unsigned lo = (unsigned)p;
        int tl = (lo >> 17) & (BW - 1);
        int pos = atomicAdd(&c[tl], 1);
        ep[pos] = (long long)(lo & 0x1FFFFu) | (p & 0xFFFFFFFF00000000ll);
    }
}

// ---------------- S = X @ W + b ----------------
template <int K, int COLS>
__global__ void lin_kernel(const float* __restrict__ X, const float* __restrict__ W,
                           const float* __restrict__ B, float* __restrict__ S,
                           int n) {
    constexpr int C4 = COLS / 4;
    __shared__ float4 Wl[K * C4];
    __shared__ float Bl[COLS];
    for (int i = threadIdx.x; i < K * C4; i += blockDim.x)
        Wl[i] = ((const float4*)W)[i];
    for (int i = threadIdx.x; i < COLS; i += blockDim.x) Bl[i] = B[i];
    __syncthreads();
    int idx = blockIdx.x * blockDim.x + threadIdx.x;
    int total = n * C4;
    if (idx >= total) return;
    int row = idx / C4;
    int c4 = idx - row * C4;
    const float* xr = X + (long)row * K;
    float4 acc;
    acc.x = Bl[4 * c4 + 0];
    acc.y = Bl[4 * c4 + 1];
    acc.z = Bl[4 * c4 + 2];
    acc.w = Bl[4 * c4 + 3];
#pragma unroll 4
    for (int k = 0; k < K; ++k) {
        float xv = xr[k];
        float4 w = Wl[k * C4 + c4];
        acc.x = fmaf(xv, w.x, acc.x);
        acc.y = fmaf(xv, w.y, acc.y);
        acc.z = fmaf(xv, w.z, acc.z);
        acc.w = fmaf(xv, w.w, acc.w);
    }
    ((float4*)S)[idx] = acc;
}

// ---------------- quarter-wave aggregation ----------------
// wave = 1 node; quarter q takes edge j+4k+q; lane loads float4 of source row.
// 16 edges in flight (4 chains/quarter) to hide gather latency.
#define FMA4(A, V, W4)                                                        \
    A.x = fmaf(V.x, W4, A.x); A.y = fmaf(V.y, W4, A.y);                       \
    A.z = fmaf(V.z, W4, A.z); A.w = fmaf(V.w, W4, A.w);

#define AGG4_BODY(R4)                                                         \
    int beg = rowptr[wid], end = rowptr[wid + 1];                             \
    float4 a0 = make_float4(0.f, 0.f, 0.f, 0.f), a1 = a0, a2 = a0, a3 = a0;   \
    int j = beg;                                                              \
    for (; j + 16 <= end; j += 16) {                                          \
        long long p0 = ep[j + q], p1 = ep[j + 4 + q];                         \
        long long p2 = ep[j + 8 + q], p3 = ep[j + 12 + q];                    \
        float4 v0 = S4[(long)(int)(unsigned)p0 * R4 + sub];                   \
        float4 v1 = S4[(long)(int)(unsigned)p1 * R4 + sub];                   \
        float4 v2 = S4[(long)(int)(unsigned)p2 * R4 + sub];                   \
        float4 v3 = S4[(long)(int)(unsigned)p3 * R4 + sub];                   \
        float w0 = __int_as_float((int)(p0 >> 32));                           \
        float w1 = __int_as_float((int)(p1 >> 32));                           \
        float w2 = __int_as_float((int)(p2 >> 32));                           \
        float w3 = __int_as_float((int)(p3 >> 32));                           \
        FMA4(a0, v0, w0) FMA4(a1, v1, w1) FMA4(a2, v2, w2) FMA4(a3, v3, w3)   \
    }                                                                         \
    for (; j + 4 <= end; j += 4) {                                            \
        long long p0 = ep[j + q];                                             \
        float4 v0 = S4[(long)(int)(unsigned)p0 * R4 + sub];                   \
        float w0 = __int_as_float((int)(p0 >> 32));                           \
        FMA4(a0, v0, w0)                                                      \
    }                                                                         \
    if (j < end) {                                                            \
        int eidx = j + q;                                                     \
        long long p0 = ep[(eidx < end) ? eidx : (end - 1)];                   \
        float4 v0 = S4[(long)(int)(unsigned)p0 * R4 + sub];                   \
        float w0 = (eidx < end) ? __int_as_float((int)(p0 >> 32)) : 0.f;      \
        FMA4(a0, v0, w0)                                                      \
    }                                                                         \
    float4 acc;                                                               \
    acc.x = (a0.x + a1.x) + (a2.x + a3.x);                                    \
    acc.y = (a0.y + a1.y) + (a2.y + a3.y);                                    \
    acc.z = (a0.z + a1.z) + (a2.z + a3.z);                                    \
    acc.w = (a0.w + a1.w) + (a2.w + a3.w);                                    \
    acc.x += __shfl_xor(acc.x, 16); acc.y += __shfl_xor(acc.y, 16);           \
    acc.z += __shfl_xor(acc.z, 16); acc.w += __shfl_xor(acc.w, 16);           \
    acc.x += __shfl_xor(acc.x, 32); acc.y += __shfl_xor(acc.y, 32);           \
    acc.z += __shfl_xor(acc.z, 32); acc.w += __shfl_xor(acc.w, 32);

// layer 0 epilogue: relu
__global__ void agg_relu_kernel(const float4* __restrict__ S4,
                                const int* __restrict__ rowptr,
                                const long long* __restrict__ ep,
                                float4* __restrict__ H4, int n) {
    int wid = (blockIdx.x * blockDim.x + threadIdx.x) >> 6;
    int lane = threadIdx.x & 63;
    int q = lane >> 4, sub = lane & 15;
    if (wid >= n) return;
    AGG4_BODY(16)
    if (q != 0) return;
    H4[(long)wid * 16 + sub] = make_float4(fmaxf(acc.x, 0.f), fmaxf(acc.y, 0.f),
                                           fmaxf(acc.z, 0.f), fmaxf(acc.w, 0.f));
}

// layers 1-2: relu + groupnorm (pairs (x,y),(z,w) lane-local) + residual
__global__ void agg_gn_kernel(const float4* __restrict__ S4,
                              const int* __restrict__ rowptr,
                              const long long* __restrict__ ep,
                              const float4* __restrict__ gamma,
                              const float4* __restrict__ beta,
                              float4* __restrict__ H4, int n) {
    int wid = (blockIdx.x * blockDim.x + threadIdx.x) >> 6;
    int lane = threadIdx.x & 63;
    int q = lane >> 4, sub = lane & 15;
    if (wid >= n) return;
    AGG4_BODY(16)
    if (q != 0) return;
    float p0 = fmaxf(acc.x, 0.f), p1 = fmaxf(acc.y, 0.f);
    float p2 = fmaxf(acc.z, 0.f), p3 = fmaxf(acc.w, 0.f);
    float dA = 0.5f * (p0 - p1);
    float dB = 0.5f * (p2 - p3);
    float rsA = rsqrtf(dA * dA + EPS);
    float rsB = rsqrtf(dB * dB + EPS);
    float4 g = gamma[sub], be = beta[sub];
    long off = (long)wid * 16 + sub;
    float4 h = H4[off];
    h.x += dA * rsA * g.x + be.x;
    h.y += -dA * rsA * g.y + be.y;
    h.z += dB * rsB * g.z + be.z;
    h.w += -dB * rsB * g.w + be.w;
    H4[off] = h;
}

// layer 3: log_softmax over 40 classes (10 float4 per row; sub<10 valid)
__global__ void agg_lsm_kernel(const float4* __restrict__ S4,
                               const int* __restrict__ rowptr,
                               const long long* __restrict__ ep,
                               float4* __restrict__ out4, int n) {
    int wid = (blockIdx.x * blockDim.x + threadIdx.x) >> 6;
    int lane = threadIdx.x & 63;
    int q = lane >> 4;
    int sub0 = lane & 15;
    int sub = (sub0 < 10) ? sub0 : 9;  // clamp: in-bounds dup loads, ignored
    if (wid >= n) return;
    AGG4_BODY(10)
    bool valid = sub0 < 10;
    float m = valid ? fmaxf(fmaxf(acc.x, acc.y), fmaxf(acc.z, acc.w)) : -INFINITY;
#pragma unroll
    for (int mk = 8; mk; mk >>= 1) m = fmaxf(m, __shfl_xor(m, mk));
    float ex = valid ? (expf(acc.x - m) + expf(acc.y - m) +
                        expf(acc.z - m) + expf(acc.w - m)) : 0.f;
#pragma unroll
    for (int mk = 8; mk; mk >>= 1) ex += __shfl_xor(ex, mk);
    float l = m + logf(ex);
    if (q == 0 && valid)
        out4[(long)wid * 10 + sub0] =
            make_float4(acc.x - l, acc.y - l, acc.z - l, acc.w - l);
}

extern "C" void kernel_launch(void* const* d_in, const int* in_sizes, int n_in,
                              void* d_out, int out_size, void* d_ws,
                              size_t ws_size, hipStream_t stream) {
    const float* x = (const float*)d_in[0];
    const int* src = (const int*)d_in[1];
    const int* tgt = (const int*)d_in[2];
    const float* mv = (const float*)d_in[3];
    const float* W0 = (const float*)d_in[4];
    const float* b0 = (const float*)d_in[5];
    const float* W1 = (const float*)d_in[6];
    const float* b1 = (const float*)d_in[7];
    const float* W2 = (const float*)d_in[8];
    const float* b2 = (const float*)d_in[9];
    const float* W3 = (const float*)d_in[10];
    const float* b3 = (const float*)d_in[11];
    const float* g1 = (const float*)d_in[12];
    const float* beta1 = (const float*)d_in[13];
    const float* g2 = (const float*)d_in[14];
    const float* beta2 = (const float*)d_in[15];

    const int N = in_sizes[0] / 128;
    const int E = in_sizes[1];
    const int NB = (N + BW - 1) >> BSHIFT;

    float* buf_s = (float*)d_ws;               // [N,64] lin output; tmp alias
    float* buf_h = buf_s + (size_t)N * 64;     // [N,64] h / residual (in-place)
    int* rowptr = (int*)(buf_h + (size_t)N * 64);  // [N+1]
    int* cnt = rowptr + (N + 1);               // [N]
    int* bsum = cnt + N;                       // [<=1024]
    int* bcur = bsum + 1024;                   // [NB]
    long long* epack = (long long*)(((uintptr_t)(bcur + NB) + 15) & ~(uintptr_t)15);
    long long* tmp = (long long*)buf_s;        // phase-A staging (dead before lin0)

    const int BLK = 256;
    auto grid = [](long total, int blk) { return (int)((total + blk - 1) / blk); };
    const int scanBlocks = grid(N, SCAN_BLK);

    // ---- CSR build (once per call; reused by all 4 layers) ----
    hipMemsetAsync(cnt, 0, (size_t)N * sizeof(int), stream);
    count_kernel<<<grid(E, BLK), BLK, 0, stream>>>(tgt, cnt, E);
    scan_p1<<<scanBlocks, SCAN_BLK, 0, stream>>>(cnt, bsum, N);
    scan_p2<<<1, 1024, 0, stream>>>(bsum, scanBlocks);
    scan_p3<<<scanBlocks, SCAN_BLK, 0, stream>>>(cnt, bsum, rowptr, N);
    bcur_init<<<grid(NB, BLK), BLK, 0, stream>>>(rowptr, bcur, NB);
    binA_kernel<<<grid(E, BLK), BLK, 0, stream>>>(src, tgt, mv, bcur, tmp, E);
    binB_kernel<<<NB, BLK, 0, stream>>>(rowptr, tmp, epack, N);

    const int aggBlocks = grid((long)N * 64, BLK);  // 4 waves (nodes) per block

    // ---- layer 0: h = relu(gcn(x, W0, b0)) ----
    lin_kernel<128, 64><<<grid((long)N * 16, BLK), BLK, 0, stream>>>(x, W0, b0, buf_s, N);
    agg_relu_kernel<<<aggBlocks, BLK, 0, stream>>>((const float4*)buf_s, rowptr, epack,
                                                   (float4*)buf_h, N);

    // ---- layer 1 ----
    lin_kernel<64, 64><<<grid((long)N * 16, BLK), BLK, 0, stream>>>(buf_h, W1, b1, buf_s, N);
    agg_gn_kernel<<<aggBlocks, BLK, 0, stream>>>((const float4*)buf_s, rowptr, epack,
                                                 (const float4*)g1, (const float4*)beta1,
                                                 (float4*)buf_h, N);

    // ---- layer 2 ----
    lin_kernel<64, 64><<<grid((long)N * 16, BLK), BLK, 0, stream>>>(buf_h, W2, b2, buf_s, N);
    agg_gn_kernel<<<aggBlocks, BLK, 0, stream>>>((const float4*)buf_s, rowptr, epack,
                                                 (const float4*)g2, (const float4*)beta2,
                                                 (float4*)buf_h, N);

    // ---- layer 3: out = log_softmax(gcn(h, W3, b3)) ----
    lin_kernel<64, 40><<<grid((long)N * 10, BLK), BLK, 0, stream>>>(buf_h, W3, b3, buf_s, N);
    agg_lsm_kernel<<<aggBlocks, BLK, 0, stream>>>((const float4*)buf_s, rowptr, epack,
                                                  (float4*)d_out, N);
}

// Round 8
// 398.220 us; speedup vs baseline: 1.6135x; 1.6135x over previous
//
#include <hip/hip_runtime.h>
#include <hip/hip_bf16.h>
#include <math.h>

// ---------------------------------------------------------------------------
// RESKnorm GCN, CSR-based (no float atomics), f32 message matrix.
//   CSR build: histogram + 3-phase scan + direct scatter fill with PER-NODE
//   cursors (50k counters -> ~16 atomics/address; R7's 391-bucket binning hit
//   the atomic-serialization cliff at 2046/address and cost 282us).
//   fill is FUSED with lin0 in one dispatch (disjoint block ranges): fill is
//   random-write-bound (VALUBusy ~0.4%), lin0 is VALU-bound -> they overlap.
//   Per layer: S = X@W+b (lin), then quarter-wave aggregation (16 edges in
//   flight per wave), fused epilogue (relu / relu+GN+residual / log_softmax).
// N=50000, E=800000, NFEAT=128, NHID=64, NCLASS=40, GROUPS=32 (2 ch/group)
// ---------------------------------------------------------------------------

#define EPS 1e-5f
#define SCAN_BLK 256

// ---------------- CSR build ----------------
__global__ void count_kernel(const int* __restrict__ tgt, int* __restrict__ cnt,
                             int E) {
    int e = blockIdx.x * blockDim.x + threadIdx.x;
    if (e < E) atomicAdd(&cnt[tgt[e]], 1);
}

__global__ void scan_p1(const int* __restrict__ cnt, int* __restrict__ bsum,
                        int n) {
    __shared__ int lds[SCAN_BLK];
    int i = blockIdx.x * SCAN_BLK + threadIdx.x;
    lds[threadIdx.x] = (i < n) ? cnt[i] : 0;
    __syncthreads();
    for (int off = SCAN_BLK / 2; off; off >>= 1) {
        if (threadIdx.x < off) lds[threadIdx.x] += lds[threadIdx.x + off];
        __syncthreads();
    }
    if (threadIdx.x == 0) bsum[blockIdx.x] = lds[0];
}

__global__ void scan_p2(int* __restrict__ bsum, int nblocks) {
    __shared__ int lds[1024];
    int tid = threadIdx.x;
    int v = (tid < nblocks) ? bsum[tid] : 0;
    lds[tid] = v;
    __syncthreads();
    for (int off = 1; off < 1024; off <<= 1) {
        int t = (tid >= off) ? lds[tid - off] : 0;
        __syncthreads();
        lds[tid] += t;
        __syncthreads();
    }
    if (tid < nblocks) bsum[tid] = lds[tid] - v;  // exclusive
}

__global__ void scan_p3(const int* __restrict__ cnt, const int* __restrict__ bsum,
                        int* __restrict__ rowptr, int* __restrict__ cursor,
                        int n) {
    __shared__ int lds[SCAN_BLK];
    int i = blockIdx.x * SCAN_BLK + threadIdx.x;
    int v = (i < n) ? cnt[i] : 0;
    lds[threadIdx.x] = v;
    __syncthreads();
    for (int off = 1; off < SCAN_BLK; off <<= 1) {
        int t = (threadIdx.x >= off) ? lds[threadIdx.x - off] : 0;
        __syncthreads();
        lds[threadIdx.x] += t;
        __syncthreads();
    }
    int excl = bsum[blockIdx.x] + lds[threadIdx.x] - v;
    if (i < n) {
        rowptr[i] = excl;
        cursor[i] = excl;
        if (i == n - 1) rowptr[n] = excl + v;
    }
}

// ---------------- fused fill (CSR scatter) + lin0 (X@W0+b0) ----------------
// blocks [0, fillBlocks): scatter packed edge {src, wbits} to ep[cursor[tgt]++]
// blocks [fillBlocks, ..): lin<128,64> producing S = x@W0+b0
__global__ void fill_lin0_kernel(const int* __restrict__ src,
                                 const int* __restrict__ tgt,
                                 const float* __restrict__ mv,
                                 int* __restrict__ cursor,
                                 long long* __restrict__ ep, int E,
                                 const float* __restrict__ X,
                                 const float* __restrict__ W,
                                 const float* __restrict__ B,
                                 float* __restrict__ S, int n,
                                 int fillBlocks) {
    constexpr int K = 128, COLS = 64, C4 = 16;
    __shared__ float4 Wl[K * C4];
    __shared__ float Bl[COLS];
    if (blockIdx.x < (unsigned)fillBlocks) {
        int e = blockIdx.x * blockDim.x + threadIdx.x;
        if (e >= E) return;
        int pos = atomicAdd(&cursor[tgt[e]], 1);
        long long v = (long long)(unsigned)src[e] |
                      ((long long)__float_as_int(mv[e]) << 32);
        ep[pos] = v;
        return;
    }
    // ---- lin0 path ----
    for (int i = threadIdx.x; i < K * C4; i += blockDim.x)
        Wl[i] = ((const float4*)W)[i];
    for (int i = threadIdx.x; i < COLS; i += blockDim.x) Bl[i] = B[i];
    __syncthreads();
    int idx = (blockIdx.x - fillBlocks) * blockDim.x + threadIdx.x;
    int total = n * C4;
    if (idx >= total) return;
    int row = idx / C4;
    int c4 = idx - row * C4;
    const float* xr = X + (long)row * K;
    float4 acc;
    acc.x = Bl[4 * c4 + 0];
    acc.y = Bl[4 * c4 + 1];
    acc.z = Bl[4 * c4 + 2];
    acc.w = Bl[4 * c4 + 3];
#pragma unroll 4
    for (int k = 0; k < K; ++k) {
        float xv = xr[k];
        float4 w = Wl[k * C4 + c4];
        acc.x = fmaf(xv, w.x, acc.x);
        acc.y = fmaf(xv, w.y, acc.y);
        acc.z = fmaf(xv, w.z, acc.z);
        acc.w = fmaf(xv, w.w, acc.w);
    }
    ((float4*)S)[idx] = acc;
}

// ---------------- S = X @ W + b (layers 1..3) ----------------
template <int K, int COLS>
__global__ void lin_kernel(const float* __restrict__ X, const float* __restrict__ W,
                           const float* __restrict__ B, float* __restrict__ S,
                           int n) {
    constexpr int C4 = COLS / 4;
    __shared__ float4 Wl[K * C4];
    __shared__ float Bl[COLS];
    for (int i = threadIdx.x; i < K * C4; i += blockDim.x)
        Wl[i] = ((const float4*)W)[i];
    for (int i = threadIdx.x; i < COLS; i += blockDim.x) Bl[i] = B[i];
    __syncthreads();
    int idx = blockIdx.x * blockDim.x + threadIdx.x;
    int total = n * C4;
    if (idx >= total) return;
    int row = idx / C4;
    int c4 = idx - row * C4;
    const float* xr = X + (long)row * K;
    float4 acc;
    acc.x = Bl[4 * c4 + 0];
    acc.y = Bl[4 * c4 + 1];
    acc.z = Bl[4 * c4 + 2];
    acc.w = Bl[4 * c4 + 3];
#pragma unroll 4
    for (int k = 0; k < K; ++k) {
        float xv = xr[k];
        float4 w = Wl[k * C4 + c4];
        acc.x = fmaf(xv, w.x, acc.x);
        acc.y = fmaf(xv, w.y, acc.y);
        acc.z = fmaf(xv, w.z, acc.z);
        acc.w = fmaf(xv, w.w, acc.w);
    }
    ((float4*)S)[idx] = acc;
}

// ---------------- quarter-wave aggregation ----------------
// wave = 1 node; quarter q takes edge j+4k+q; lane loads float4 of source row.
// 16 edges in flight (4 chains/quarter) to hide gather latency.
#define FMA4(A, V, W4)                                                        \
    A.x = fmaf(V.x, W4, A.x); A.y = fmaf(V.y, W4, A.y);                       \
    A.z = fmaf(V.z, W4, A.z); A.w = fmaf(V.w, W4, A.w);

#define AGG4_BODY(R4)                                                         \
    int beg = rowptr[wid], end = rowptr[wid + 1];                             \
    float4 a0 = make_float4(0.f, 0.f, 0.f, 0.f), a1 = a0, a2 = a0, a3 = a0;   \
    int j = beg;                                                              \
    for (; j + 16 <= end; j += 16) {                                          \
        long long p0 = ep[j + q], p1 = ep[j + 4 + q];                         \
        long long p2 = ep[j + 8 + q], p3 = ep[j + 12 + q];                    \
        float4 v0 = S4[(long)(int)(unsigned)p0 * R4 + sub];                   \
        float4 v1 = S4[(long)(int)(unsigned)p1 * R4 + sub];                   \
        float4 v2 = S4[(long)(int)(unsigned)p2 * R4 + sub];                   \
        float4 v3 = S4[(long)(int)(unsigned)p3 * R4 + sub];                   \
        float w0 = __int_as_float((int)(p0 >> 32));                           \
        float w1 = __int_as_float((int)(p1 >> 32));                           \
        float w2 = __int_as_float((int)(p2 >> 32));                           \
        float w3 = __int_as_float((int)(p3 >> 32));                           \
        FMA4(a0, v0, w0) FMA4(a1, v1, w1) FMA4(a2, v2, w2) FMA4(a3, v3, w3)   \
    }                                                                         \
    for (; j + 4 <= end; j += 4) {                                            \
        long long p0 = ep[j + q];                                             \
        float4 v0 = S4[(long)(int)(unsigned)p0 * R4 + sub];                   \
        float w0 = __int_as_float((int)(p0 >> 32));                           \
        FMA4(a0, v0, w0)                                                      \
    }                                                                         \
    if (j < end) {                                                            \
        int eidx = j + q;                                                     \
        long long p0 = ep[(eidx < end) ? eidx : (end - 1)];                   \
        float4 v0 = S4[(long)(int)(unsigned)p0 * R4 + sub];                   \
        float w0 = (eidx < end) ? __int_as_float((int)(p0 >> 32)) : 0.f;      \
        FMA4(a0, v0, w0)                                                      \
    }                                                                         \
    float4 acc;                                                               \
    acc.x = (a0.x + a1.x) + (a2.x + a3.x);                                    \
    acc.y = (a0.y + a1.y) + (a2.y + a3.y);                                    \
    acc.z = (a0.z + a1.z) + (a2.z + a3.z);                                    \
    acc.w = (a0.w + a1.w) + (a2.w + a3.w);                                    \
    acc.x += __shfl_xor(acc.x, 16); acc.y += __shfl_xor(acc.y, 16);           \
    acc.z += __shfl_xor(acc.z, 16); acc.w += __shfl_xor(acc.w, 16);           \
    acc.x += __shfl_xor(acc.x, 32); acc.y += __shfl_xor(acc.y, 32);           \
    acc.z += __shfl_xor(acc.z, 32); acc.w += __shfl_xor(acc.w, 32);

// layer 0 epilogue: relu
__global__ void agg_relu_kernel(const float4* __restrict__ S4,
                                const int* __restrict__ rowptr,
                                const long long* __restrict__ ep,
                                float4* __restrict__ H4, int n) {
    int wid = (blockIdx.x * blockDim.x + threadIdx.x) >> 6;
    int lane = threadIdx.x & 63;
    int q = lane >> 4, sub = lane & 15;
    if (wid >= n) return;
    AGG4_BODY(16)
    if (q != 0) return;
    H4[(long)wid * 16 + sub] = make_float4(fmaxf(acc.x, 0.f), fmaxf(acc.y, 0.f),
                                           fmaxf(acc.z, 0.f), fmaxf(acc.w, 0.f));
}

// layers 1-2: relu + groupnorm (pairs (x,y),(z,w) lane-local) + residual
__global__ void agg_gn_kernel(const float4* __restrict__ S4,
                              const int* __restrict__ rowptr,
                              const long long* __restrict__ ep,
                              const float4* __restrict__ gamma,
                              const float4* __restrict__ beta,
                              float4* __restrict__ H4, int n) {
    int wid = (blockIdx.x * blockDim.x + threadIdx.x) >> 6;
    int lane = threadIdx.x & 63;
    int q = lane >> 4, sub = lane & 15;
    if (wid >= n) return;
    AGG4_BODY(16)
    if (q != 0) return;
    float p0 = fmaxf(acc.x, 0.f), p1 = fmaxf(acc.y, 0.f);
    float p2 = fmaxf(acc.z, 0.f), p3 = fmaxf(acc.w, 0.f);
    float dA = 0.5f * (p0 - p1);
    float dB = 0.5f * (p2 - p3);
    float rsA = rsqrtf(dA * dA + EPS);
    float rsB = rsqrtf(dB * dB + EPS);
    float4 g = gamma[sub], be = beta[sub];
    long off = (long)wid * 16 + sub;
    float4 h = H4[off];
    h.x += dA * rsA * g.x + be.x;
    h.y += -dA * rsA * g.y + be.y;
    h.z += dB * rsB * g.z + be.z;
    h.w += -dB * rsB * g.w + be.w;
    H4[off] = h;
}

// layer 3: log_softmax over 40 classes (10 float4 per row; sub<10 valid)
__global__ void agg_lsm_kernel(const float4* __restrict__ S4,
                               const int* __restrict__ rowptr,
                               const long long* __restrict__ ep,
                               float4* __restrict__ out4, int n) {
    int wid = (blockIdx.x * blockDim.x + threadIdx.x) >> 6;
    int lane = threadIdx.x & 63;
    int q = lane >> 4;
    int sub0 = lane & 15;
    int sub = (sub0 < 10) ? sub0 : 9;  // clamp: in-bounds dup loads, ignored
    if (wid >= n) return;
    AGG4_BODY(10)
    bool valid = sub0 < 10;
    float m = valid ? fmaxf(fmaxf(acc.x, acc.y), fmaxf(acc.z, acc.w)) : -INFINITY;
#pragma unroll
    for (int mk = 8; mk; mk >>= 1) m = fmaxf(m, __shfl_xor(m, mk));
    float ex = valid ? (expf(acc.x - m) + expf(acc.y - m) +
                        expf(acc.z - m) + expf(acc.w - m)) : 0.f;
#pragma unroll
    for (int mk = 8; mk; mk >>= 1) ex += __shfl_xor(ex, mk);
    float l = m + logf(ex);
    if (q == 0 && valid)
        out4[(long)wid * 10 + sub0] =
            make_float4(acc.x - l, acc.y - l, acc.z - l, acc.w - l);
}

extern "C" void kernel_launch(void* const* d_in, const int* in_sizes, int n_in,
                              void* d_out, int out_size, void* d_ws,
                              size_t ws_size, hipStream_t stream) {
    const float* x = (const float*)d_in[0];
    const int* src = (const int*)d_in[1];
    const int* tgt = (const int*)d_in[2];
    const float* mv = (const float*)d_in[3];
    const float* W0 = (const float*)d_in[4];
    const float* b0 = (const float*)d_in[5];
    const float* W1 = (const float*)d_in[6];
    const float* b1 = (const float*)d_in[7];
    const float* W2 = (const float*)d_in[8];
    const float* b2 = (const float*)d_in[9];
    const float* W3 = (const float*)d_in[10];
    const float* b3 = (const float*)d_in[11];
    const float* g1 = (const float*)d_in[12];
    const float* beta1 = (const float*)d_in[13];
    const float* g2 = (const float*)d_in[14];
    const float* beta2 = (const float*)d_in[15];

    const int N = in_sizes[0] / 128;
    const int E = in_sizes[1];

    float* buf_s = (float*)d_ws;               // [N,64] linear output (f32)
    float* buf_h = buf_s + (size_t)N * 64;     // [N,64] h / residual (in-place)
    int* rowptr = (int*)(buf_h + (size_t)N * 64);  // [N+1]
    int* cursor = rowptr + (N + 1);            // [N]
    int* cnt = cursor + N;                     // [N]
    int* bsum = cnt + N;                       // [<=1024]
    long long* epack = (long long*)(((uintptr_t)(bsum + 1024) + 15) & ~(uintptr_t)15);

    const int BLK = 256;
    auto grid = [](long total, int blk) { return (int)((total + blk - 1) / blk); };
    const int scanBlocks = grid(N, SCAN_BLK);
    const int fillBlocks = grid(E, BLK);
    const int lin0Blocks = grid((long)N * 16, BLK);

    // ---- CSR build (once per call; reused by all 4 layers) ----
    hipMemsetAsync(cnt, 0, (size_t)N * sizeof(int), stream);
    count_kernel<<<grid(E, BLK), BLK, 0, stream>>>(tgt, cnt, E);
    scan_p1<<<scanBlocks, SCAN_BLK, 0, stream>>>(cnt, bsum, N);
    scan_p2<<<1, 1024, 0, stream>>>(bsum, scanBlocks);
    scan_p3<<<scanBlocks, SCAN_BLK, 0, stream>>>(cnt, bsum, rowptr, cursor, N);

    // ---- fused: CSR fill + layer-0 linear (independent, complementary) ----
    fill_lin0_kernel<<<fillBlocks + lin0Blocks, BLK, 0, stream>>>(
        src, tgt, mv, cursor, epack, E, x, W0, b0, buf_s, N, fillBlocks);

    const int aggBlocks = grid((long)N * 64, BLK);  // 4 waves (nodes) per block

    // ---- layer 0: h = relu(gcn(x, W0, b0)) ----
    agg_relu_kernel<<<aggBlocks, BLK, 0, stream>>>((const float4*)buf_s, rowptr, epack,
                                                   (float4*)buf_h, N);

    // ---- layer 1 ----
    lin_kernel<64, 64><<<grid((long)N * 16, BLK), BLK, 0, stream>>>(buf_h, W1, b1, buf_s, N);
    agg_gn_kernel<<<aggBlocks, BLK, 0, stream>>>((const float4*)buf_s, rowptr, epack,
                                                 (const float4*)g1, (const float4*)beta1,
                                                 (float4*)buf_h, N);

    // ---- layer 2 ----
    lin_kernel<64, 64><<<grid((long)N * 16, BLK), BLK, 0, stream>>>(buf_h, W2, b2, buf_s, N);
    agg_gn_kernel<<<aggBlocks, BLK, 0, stream>>>((const float4*)buf_s, rowptr, epack,
                                                 (const float4*)g2, (const float4*)beta2,
                                                 (float4*)buf_h, N);

    // ---- layer 3: out = log_softmax(gcn(h, W3, b3)) ----
    lin_kernel<64, 40><<<grid((long)N * 10, BLK), BLK, 0, stream>>>(buf_h, W3, b3, buf_s, N);
    agg_lsm_kernel<<<aggBlocks, BLK, 0, stream>>>((const float4*)buf_s, rowptr, epack,
                                                  (float4*)d_out, N);
}